// Round 1
// baseline (370.640 us; speedup 1.0000x reference)
//
#include <hip/hip_runtime.h>
#include <stdint.h>
#include <stddef.h>

// Problem constants
// B=2, S=2048, E=1024, H=16, D=64, KV=1, QKV_OUT=1152
#define SEQ   2048
#define EMB   1024
#define NHEAD 16
#define HDIM  64
#define QKVO  1152
#define MTOT  4096   // B*S

typedef __attribute__((ext_vector_type(4))) float f32x4;
typedef __attribute__((ext_vector_type(8))) short short8;  // 8 bf16

__device__ __forceinline__ short f2bf(float f) {
  union { float f; unsigned u; } v; v.f = f;
  unsigned r = v.u + 0x7FFFu + ((v.u >> 16) & 1u);   // RNE
  return (short)(r >> 16);
}

__device__ __forceinline__ void gload16(const void* g, void* l) {
  __builtin_amdgcn_global_load_lds((const __attribute__((address_space(1))) void*)g,
                                   (__attribute__((address_space(3))) void*)l,
                                   16, 0, 0);
}

// ---------------- prep: bf16 casts + rope tables ----------------
// chunks of 8 elems: x: 524288, wqkv: 147456, wout: 131072, rope: 8192
#define PX   524288
#define PW1  671744
#define PW2  802816
#define PTOT 811008

__device__ __forceinline__ void cvt8(const float* __restrict__ s, short* __restrict__ d) {
  float4 a = ((const float4*)s)[0];
  float4 b = ((const float4*)s)[1];
  short8 r;
  r[0]=f2bf(a.x); r[1]=f2bf(a.y); r[2]=f2bf(a.z); r[3]=f2bf(a.w);
  r[4]=f2bf(b.x); r[5]=f2bf(b.y); r[6]=f2bf(b.z); r[7]=f2bf(b.w);
  *(short8*)d = r;
}

__global__ __launch_bounds__(256) void prep_kernel(
    const float* __restrict__ x, const float* __restrict__ wqkv, const float* __restrict__ wout,
    short* __restrict__ xb, short* __restrict__ wqkvb, short* __restrict__ woutb,
    float* __restrict__ cost, float* __restrict__ sint) {
  int c = blockIdx.x * 256 + threadIdx.x;
  if (c < PX) {
    cvt8(x + (size_t)c * 8, xb + (size_t)c * 8);
  } else if (c < PW1) {
    int c2 = c - PX;
    cvt8(wqkv + (size_t)c2 * 8, wqkvb + (size_t)c2 * 8);
  } else if (c < PW2) {
    int c2 = c - PW1;
    cvt8(wout + (size_t)c2 * 8, woutb + (size_t)c2 * 8);
  } else if (c < PTOT) {
    int c2 = c - PW2;
    #pragma unroll
    for (int t = 0; t < 8; ++t) {
      int idx = c2 * 8 + t;
      int pos = idx >> 5, i = idx & 31;
      float inv = powf(10000.0f, -(float)i * (1.0f / 32.0f));
      float ang = (float)pos * inv;
      float sv, cv;
      sincosf(ang, &sv, &cv);
      cost[idx] = cv; sint[idx] = sv;
    }
  }
}

// ---------------- shared GEMM mainloop: 128x128 tile, BK=64 ----------------
// A [M][1024] bf16 row-major, B [N][1024] bf16 row-major (B^T input form).
// 256 threads = 4 waves (2x2), each wave 64x64 = 4x4 fragments of 16x16x32.
__device__ __forceinline__ void gemm_mainloop(
    const short* __restrict__ A, const short* __restrict__ Bm,
    int m0, int n0, short* lsA, short* lsB, f32x4 acc[4][4]) {
  const int w = threadIdx.x >> 6, lane = threadIdx.x & 63;
  const int wm = w >> 1, wn = w & 1;
  const int lrow = lane & 15, lk = (lane >> 4) * 8;
  #pragma unroll
  for (int mi = 0; mi < 4; ++mi)
    #pragma unroll
    for (int ni = 0; ni < 4; ++ni)
      acc[mi][ni] = (f32x4){0.f, 0.f, 0.f, 0.f};

  const int srow8 = lane >> 3;        // 0..7 within 8-row segment
  const int scol = (lane & 7) * 8;    // 0..56

  for (int kt = 0; kt < 1024; kt += 64) {
    #pragma unroll
    for (int ii = 0; ii < 4; ++ii) {
      int seg = w * 4 + ii;            // 0..15, 8 rows each
      int row = seg * 8 + srow8;
      gload16(A  + (size_t)(m0 + row) * 1024 + kt + scol, lsA + seg * 512);
      gload16(Bm + (size_t)(n0 + row) * 1024 + kt + scol, lsB + seg * 512);
    }
    __syncthreads();   // compiler drains vmcnt before barrier -> LDS tiles valid
    #pragma unroll
    for (int ks = 0; ks < 2; ++ks) {
      short8 af[4], bfv[4];
      #pragma unroll
      for (int mi = 0; mi < 4; ++mi)
        af[mi] = *(const short8*)(lsA + (wm * 64 + mi * 16 + lrow) * 64 + lk + ks * 32);
      #pragma unroll
      for (int ni = 0; ni < 4; ++ni)
        bfv[ni] = *(const short8*)(lsB + (wn * 64 + ni * 16 + lrow) * 64 + lk + ks * 32);
      #pragma unroll
      for (int mi = 0; mi < 4; ++mi)
        #pragma unroll
        for (int ni = 0; ni < 4; ++ni)
          acc[mi][ni] = __builtin_amdgcn_mfma_f32_16x16x32_bf16(af[mi], bfv[ni], acc[mi][ni], 0, 0, 0);
    }
    __syncthreads();   // protect LDS before next-stage overwrite
  }
}

// ---------------- QKV GEMM + bias + RoPE + scatter ----------------
__global__ __launch_bounds__(256) void qkv_kernel(
    const short* __restrict__ xb, const short* __restrict__ wb,
    const float* __restrict__ bias, const float* __restrict__ cost, const float* __restrict__ sint,
    short* __restrict__ qbuf, short* __restrict__ kbuf, short* __restrict__ vt) {
  __shared__ __align__(16) short lsA[8192];
  __shared__ __align__(16) short lsB[8192];
  f32x4 acc[4][4];
  const int m0 = blockIdx.x * 128, n0 = blockIdx.y * 128;
  gemm_mainloop(xb, wb, m0, n0, lsA, lsB, acc);

  const int w = threadIdx.x >> 6, lane = threadIdx.x & 63;
  const int wm = w >> 1, wn = w & 1;
  const int colb = n0 + wn * 64 + (lane & 15);
  const int rowb = m0 + wm * 64 + ((lane >> 4) << 2);
  #pragma unroll
  for (int ni = 0; ni < 4; ++ni) {
    const int col = colb + ni * 16;
    const float bv = bias[col];
    #pragma unroll
    for (int mi = 0; mi < 4; ++mi) {
      #pragma unroll
      for (int j = 0; j < 4; ++j) {
        const int m = rowb + mi * 16 + j;
        const int bb = m >> 11, pos = m & 2047;
        float v = acc[mi][ni][j] + bv;
        float vp = __shfl_xor(v, 1);   // rope pair partner (col^1, same row)
        float ov;
        if (col < 1088) {              // q or k -> rope
          const int d = (col < 1024) ? (col & 63) : (col - 1024);
          const int i = d >> 1;
          const float cv = cost[pos * 32 + i], sv = sint[pos * 32 + i];
          ov = ((col & 1) == 0) ? (v * cv - vp * sv)    // even: x1*c - x2*s
                                : (vp * sv + v * cv);   // odd:  x1*s + x2*c
          if (col < 1024) ov *= 0.125f;                 // fold 1/sqrt(64) into q
        } else {
          ov = v;
        }
        const short bfo = f2bf(ov);
        if (col < 1024) {
          const int h = col >> 6;
          qbuf[(((size_t)bb * NHEAD + h) * SEQ + pos) * HDIM + (col & 63)] = bfo;
        } else if (col < 1088) {
          kbuf[((size_t)bb * SEQ + pos) * HDIM + (col - 1024)] = bfo;
        } else {
          vt[((size_t)bb * HDIM + (col - 1088)) * SEQ + pos] = bfo;   // V transposed [B][D][S]
        }
      }
    }
  }
}

// ---------------- flash attention (causal, MQA) ----------------
// grid (32, 32): x = 64-row q chunk, y = b*16+h. 4 waves/block, each wave
// owns 16 q rows independently. KVBLK=32. q pre-scaled by 0.125.
__global__ __launch_bounds__(256) void attn_kernel(
    const short* __restrict__ qb, const short* __restrict__ kb,
    const short* __restrict__ vt, short* __restrict__ ao) {
  __shared__ __align__(16) short plds[4][16][40];   // per-wave P tile, padded
  const int w = threadIdx.x >> 6, lane = threadIdx.x & 63;
  const int bh = blockIdx.y, bb = bh >> 4, h = bh & 15;
  const int q0 = blockIdx.x * 64 + w * 16;
  const int g = lane >> 4, qloc = lane & 15;
  const int qg = q0 + qloc;

  const short* qbase = qb + (((size_t)bb * NHEAD + h) * SEQ + q0 + qloc) * HDIM + g * 8;
  short8 qf0 = *(const short8*)qbase;
  short8 qf1 = *(const short8*)(qbase + 32);

  f32x4 o[4];
  #pragma unroll
  for (int nf = 0; nf < 4; ++nf) o[nf] = (f32x4){0.f, 0.f, 0.f, 0.f};
  float m_run = -3.0e38f, l_run = 0.0f;

  short* prow = &plds[w][qloc][0];
  const short* pread = &plds[w][qloc][g * 8];
  const int nt = (q0 + 16 + 31) >> 5;

  for (int t = 0; t < nt; ++t) {
    const int kv0 = t << 5;
    // swapped QK^T: S^T = K * Q^T  (A = K rows, B = Q rows)
    const short* kbase = kb + ((size_t)bb * SEQ + kv0 + qloc) * HDIM + g * 8;
    short8 kf00 = *(const short8*)(kbase);
    short8 kf01 = *(const short8*)(kbase + 32);
    short8 kf10 = *(const short8*)(kbase + 16 * HDIM);
    short8 kf11 = *(const short8*)(kbase + 16 * HDIM + 32);
    f32x4 st0 = (f32x4){0.f,0.f,0.f,0.f}, st1 = st0;
    st0 = __builtin_amdgcn_mfma_f32_16x16x32_bf16(kf00, qf0, st0, 0, 0, 0);
    st0 = __builtin_amdgcn_mfma_f32_16x16x32_bf16(kf01, qf1, st0, 0, 0, 0);
    st1 = __builtin_amdgcn_mfma_f32_16x16x32_bf16(kf10, qf0, st1, 0, 0, 0);
    st1 = __builtin_amdgcn_mfma_f32_16x16x32_bf16(kf11, qf1, st1, 0, 0, 0);

    // lane holds S[q = qg][kv = kv0 + r*16 + g*4 + j]
    float s[8];
    #pragma unroll
    for (int j = 0; j < 4; ++j) {
      const int kv = kv0 + g * 4 + j;
      s[j]     = (kv      <= qg) ? st0[j] : -3.0e38f;
      s[4 + j] = (kv + 16 <= qg) ? st1[j] : -3.0e38f;
    }
    float mt = fmaxf(fmaxf(fmaxf(s[0], s[1]), fmaxf(s[2], s[3])),
                     fmaxf(fmaxf(s[4], s[5]), fmaxf(s[6], s[7])));
    mt = fmaxf(mt, __shfl_xor(mt, 16));
    mt = fmaxf(mt, __shfl_xor(mt, 32));
    const float m_new = fmaxf(m_run, mt);
    const float sc = expf(m_run - m_new);
    float p[8], ps = 0.f;
    #pragma unroll
    for (int i2 = 0; i2 < 8; ++i2) { p[i2] = expf(s[i2] - m_new); ps += p[i2]; }
    ps += __shfl_xor(ps, 16);
    ps += __shfl_xor(ps, 32);
    l_run = l_run * sc + ps;
    m_run = m_new;

    // P -> LDS (bf16), re-read in A-fragment layout (wave-private, DS in-order)
    #pragma unroll
    for (int r = 0; r < 2; ++r) {
      #pragma unroll
      for (int jj = 0; jj < 4; jj += 2) {
        unsigned pk = (unsigned)(unsigned short)f2bf(p[r * 4 + jj]) |
                      ((unsigned)(unsigned short)f2bf(p[r * 4 + jj + 1]) << 16);
        *(unsigned*)(prow + r * 16 + g * 4 + jj) = pk;
      }
    }
    short8 pa = *(const short8*)pread;

    // broadcast per-row rescale to O layout (row = g*4+j)
    float scj[4];
    #pragma unroll
    for (int j = 0; j < 4; ++j) scj[j] = __shfl(sc, g * 4 + j);
    #pragma unroll
    for (int nf = 0; nf < 4; ++nf)
      #pragma unroll
      for (int j = 0; j < 4; ++j) o[nf][j] *= scj[j];

    // PV: B-fragments contiguous from transposed V
    const short* vb = vt + ((size_t)bb * HDIM + qloc) * SEQ + kv0 + g * 8;
    #pragma unroll
    for (int nf = 0; nf < 4; ++nf) {
      short8 vf = *(const short8*)(vb + (size_t)nf * 16 * SEQ);
      o[nf] = __builtin_amdgcn_mfma_f32_16x16x32_bf16(pa, vf, o[nf], 0, 0, 0);
    }
  }

  float li[4];
  #pragma unroll
  for (int j = 0; j < 4; ++j) li[j] = 1.0f / __shfl(l_run, g * 4 + j);
  const size_t obase = ((size_t)bb * SEQ + q0) * EMB + (size_t)h * HDIM + qloc;
  #pragma unroll
  for (int nf = 0; nf < 4; ++nf)
    #pragma unroll
    for (int j = 0; j < 4; ++j)
      ao[obase + (size_t)(g * 4 + j) * EMB + nf * 16] = f2bf(o[nf][j] * li[j]);
}

// ---------------- output GEMM + bias ----------------
__global__ __launch_bounds__(256) void out_kernel(
    const short* __restrict__ ab, const short* __restrict__ wb,
    const float* __restrict__ bias, float* __restrict__ out) {
  __shared__ __align__(16) short lsA[8192];
  __shared__ __align__(16) short lsB[8192];
  f32x4 acc[4][4];
  const int m0 = blockIdx.x * 128, n0 = blockIdx.y * 128;
  gemm_mainloop(ab, wb, m0, n0, lsA, lsB, acc);

  const int w = threadIdx.x >> 6, lane = threadIdx.x & 63;
  const int wm = w >> 1, wn = w & 1;
  const int colb = n0 + wn * 64 + (lane & 15);
  const int rowb = m0 + wm * 64 + ((lane >> 4) << 2);
  #pragma unroll
  for (int ni = 0; ni < 4; ++ni) {
    const int col = colb + ni * 16;
    const float bv = bias[col];
    #pragma unroll
    for (int mi = 0; mi < 4; ++mi)
      #pragma unroll
      for (int j = 0; j < 4; ++j) {
        const int m = rowb + mi * 16 + j;
        out[(size_t)m * EMB + col] = acc[mi][ni][j] + bv;
      }
  }
}

// ---------------- launch ----------------
extern "C" void kernel_launch(void* const* d_in, const int* in_sizes, int n_in,
                              void* d_out, int out_size, void* d_ws, size_t ws_size,
                              hipStream_t stream) {
  const float* x    = (const float*)d_in[0];
  const float* qkvw = (const float*)d_in[1];
  const float* qkvb = (const float*)d_in[2];
  const float* outw = (const float*)d_in[3];
  const float* outb = (const float*)d_in[4];
  float* out = (float*)d_out;
  char* ws = (char*)d_ws;

  short* xb    = (short*)(ws + 0);            // 4096x1024 bf16 (8 MB) — reused as attn_out
  short* wqkvb = (short*)(ws + 8388608);      // 1152x1024 bf16
  short* woutb = (short*)(ws + 10747904);     // 1024x1024 bf16
  float* cost  = (float*)(ws + 12845056);     // 2048x32 f32
  float* sint  = (float*)(ws + 13107200);
  short* qbuf  = (short*)(ws + 13369344);     // [B][H][S][D] bf16 (8 MB), q pre-scaled
  short* kbuf  = (short*)(ws + 21757952);     // [B][S][D] bf16
  short* vtb   = (short*)(ws + 22282240);     // [B][D][S] bf16 (transposed)
  short* aob   = xb;                          // alias: xb dead after qkv_kernel

  prep_kernel<<<3168, 256, 0, stream>>>(x, qkvw, outw, xb, wqkvb, woutb, cost, sint);
  qkv_kernel<<<dim3(32, 9), 256, 0, stream>>>(xb, wqkvb, qkvb, cost, sint, qbuf, kbuf, vtb);
  attn_kernel<<<dim3(32, 32), 256, 0, stream>>>(qbuf, kbuf, vtb, aob);
  out_kernel<<<dim3(32, 8), 256, 0, stream>>>(aob, woutb, outb, out);
}